// Round 1
// baseline (328.157 us; speedup 1.0000x reference)
//
#include <hip/hip_runtime.h>

#define Bn 512
#define Tn 1024
#define Nn 64
#define Kseg 16         // segments per sequence (waves = Bn*Kseg)
#define WPB 4           // waves per block (256-thread blocks -> up to 32 waves/CU)
#define BURN 16         // burn-in steps: direction converges ~0.35^16 ≈ 3e-8

typedef _Float16 h2 __attribute__((ext_vector_type(2)));
typedef _Float16 h8 __attribute__((ext_vector_type(8)));

#if __has_builtin(__builtin_amdgcn_fdot2)
__device__ __forceinline__ float fdot2f(h2 a, h2 b, float c) {
    return __builtin_amdgcn_fdot2(a, b, c, false);
}
#else
__device__ __forceinline__ float fdot2f(h2 a, h2 b, float c) {
    return fmaf((float)a[0], (float)b[0], fmaf((float)a[1], (float)b[1], c));
}
#endif

__device__ __forceinline__ float wave_sum(float v) {
#pragma unroll
    for (int off = 32; off >= 1; off >>= 1) v += __shfl_xor(v, off, 64);
    return v;
}

// One wave = one (batch, segment); WPB waves per block, independent (no barriers).
// Segment s covers steps t in [a_s, a_{s+1}) of the forward recursion
// u_t = E^T diag(exp(emit_{t-1})) u_{t-1}.
// s>0 starts from u=1 and runs BURN warm-up steps (Birkhoff contraction makes
// the direction exact to fp32 by then); contribution log(sum u_end) - S*ln2
// - log(sum u_start) is scale-invariant and telescopes to logZ.
__global__ __launch_bounds__(WPB * 64, 8) void crf_seg(
    const float* __restrict__ emit,
    const int*   __restrict__ target,
    const int*   __restrict__ mask,
    const float* __restrict__ trans,
    const float* __restrict__ strans,
    const float* __restrict__ etrans,
    float*       __restrict__ out)
{
    __shared__ __align__(16) _Float16 pbuf[WPB][Nn];

    const int lane = threadIdx.x & 63;
    const int wid  = threadIdx.x >> 6;
    const int gw   = blockIdx.x * WPB + wid;   // global wave id
    const int b    = gw & (Bn - 1);
    const int s    = gw >> 9;                  // 0..Kseg-1

    // E column j (j = lane) as fp16 pairs over i
    h2 E2[32];
#pragma unroll
    for (int m = 0; m < 32; ++m) {
        float x0 = trans[(2 * m) * Nn + lane];
        float x1 = trans[(2 * m + 1) * Nn + lane];
        h2 e; e[0] = (_Float16)__expf(x0); e[1] = (_Float16)__expf(x1);
        E2[m] = e;
    }

    // len = popcount of prefix mask
    const int* mrow = mask + (size_t)b * Tn;
    int lsum = 0;
#pragma unroll
    for (int k = 0; k < Tn / Nn; ++k) lsum += mrow[k * Nn + lane];
#pragma unroll
    for (int off = 32; off >= 1; off >>= 1) lsum += __shfl_xor(lsum, off, 64);
    const int len = lsum;                      // in [512, 1024]

    // segment bounds (identical arithmetic in every wave of this b)
    const int a_s = (s * len) >> 4;            // Kseg = 16
    const int a_e = ((s + 1) * len) >> 4;      // s=15 -> len
    const int tb   = s ? (a_s - BURN) : 1;     // first executed step
    const int tend = a_e - 1;                  // last executed step
    const int rec_t = s ? a_s : -1;            // record point (never hits for s=0)

    const size_t ebase = (size_t)b * Tn * Nn;

    float uu = s ? 1.0f : __expf(strans[lane]);
    int   S  = 0;
    float L0 = 0.0f;

    // w pipeline: wC[q] = exp(emit row tb-1+q); eN = raw rows tb+7..tb+14
    float wC[8], eN[8];
#pragma unroll
    for (int q = 0; q < 8; ++q) wC[q] = emit[ebase + (size_t)(tb - 1 + q) * Nn + lane];
#pragma unroll
    for (int q = 0; q < 8; ++q) eN[q] = emit[ebase + (size_t)(tb + 7 + q) * Nn + lane];
#pragma unroll
    for (int q = 0; q < 8; ++q) wC[q] = __expf(wC[q]);

    _Float16* pb = pbuf[wid];
    auto step = [&](float w) {
        int bits = __builtin_amdgcn_readfirstlane(__float_as_int(uu));
        int mk   = 127 - ((bits >> 23) & 0xff);
        S += mk;
        float p = ldexpf(uu, mk) * w;          // p in (0, ~1300) -> fp16 safe
        pb[lane] = (_Float16)p;

        const h8* pb8 = (const h8*)pb;         // 8 broadcast b128 reads, in-order DS
        float a0 = 0.f, a1 = 0.f, a2 = 0.f, a3 = 0.f;
        float a4 = 0.f, a5 = 0.f, a6 = 0.f, a7 = 0.f;
#pragma unroll
        for (int r = 0; r < 8; r += 2) {
            h8 v0 = pb8[r], v1 = pb8[r + 1];
            a0 = fdot2f(__builtin_shufflevector(v0, v0, 0, 1), E2[4 * r + 0], a0);
            a1 = fdot2f(__builtin_shufflevector(v0, v0, 2, 3), E2[4 * r + 1], a1);
            a2 = fdot2f(__builtin_shufflevector(v0, v0, 4, 5), E2[4 * r + 2], a2);
            a3 = fdot2f(__builtin_shufflevector(v0, v0, 6, 7), E2[4 * r + 3], a3);
            a4 = fdot2f(__builtin_shufflevector(v1, v1, 0, 1), E2[4 * r + 4], a4);
            a5 = fdot2f(__builtin_shufflevector(v1, v1, 2, 3), E2[4 * r + 5], a5);
            a6 = fdot2f(__builtin_shufflevector(v1, v1, 4, 5), E2[4 * r + 6], a6);
            a7 = fdot2f(__builtin_shufflevector(v1, v1, 6, 7), E2[4 * r + 7], a7);
        }
        uu = ((a0 + a1) + (a2 + a3)) + ((a4 + a5) + (a6 + a7));
    };

    int t0 = tb;
    while (t0 + 8 <= tend + 1) {
#pragma unroll
        for (int q = 0; q < 8; ++q) step(wC[q]);
#pragma unroll
        for (int q = 0; q < 8; ++q) wC[q] = __expf(eN[q]);
#pragma unroll
        for (int q = 0; q < 8; ++q) {
            int idx = t0 + 15 + q; if (idx > tend - 1) idx = tend - 1;
            eN[q] = emit[ebase + (size_t)idx * Nn + lane];
        }
        t0 += 8;
        if (t0 == rec_t) {                    // burn-in done: u = c*v_{a_s-1}
            L0 = __logf(wave_sum(uu));
            S = 0;
        }
    }
#pragma unroll
    for (int q = 0; q < 8; ++q)
        if (t0 + q <= tend) step(wC[q]);

    // segment logZ contribution
    float lend;
    if (s == Kseg - 1) {
        float eL = emit[ebase + (size_t)(len - 1) * Nn + lane];
        lend = __logf(wave_sum(uu * __expf(eL + etrans[lane])));
    } else {
        lend = __logf(wave_sum(uu));
    }
    float contrib = lend - (float)S * 0.6931471805599453f - L0;

    // gold-path score for t in [a_s, a_e)  (s=0: [0, a_1))
    const int* trow = target + (size_t)b * Tn;
    const int t_sc = s ? a_s : 0;
    float sc = 0.0f;
#pragma unroll
    for (int k = 0; k < 2; ++k) {             // covers max range 65 (<=128)
        int t = t_sc + k * Nn + lane;
        if (t < a_e) {
            int g = trow[t];
            sc += emit[ebase + (size_t)t * Nn + g];
            if (t > 0) sc += trans[trow[t - 1] * Nn + g];
        }
    }
    sc = wave_sum(sc);

    if (lane == 0) {
        if (s == 0)        sc += strans[trow[0]];
        if (s == Kseg - 1) sc += etrans[trow[len - 1]];
        atomicAdd(out, (contrib - sc) * (1.0f / (float)Bn));
    }
}

extern "C" void kernel_launch(void* const* d_in, const int* in_sizes, int n_in,
                              void* d_out, int out_size, void* d_ws, size_t ws_size,
                              hipStream_t stream) {
    const float* emit   = (const float*)d_in[0];
    const int*   target = (const int*)d_in[1];
    const int*   mask   = (const int*)d_in[2];
    const float* trans  = (const float*)d_in[3];
    const float* strans = (const float*)d_in[4];
    const float* etrans = (const float*)d_in[5];
    float* out = (float*)d_out;

    hipMemsetAsync(out, 0, sizeof(float), stream);
    crf_seg<<<Bn * Kseg / WPB, WPB * 64, 0, stream>>>(emit, target, mask, trans, strans, etrans, out);
}

// Round 3
// 291.058 us; speedup vs baseline: 1.1275x; 1.1275x over previous
//
#include <hip/hip_runtime.h>

#define Bn 512
#define Tn 1024
#define Nn 64
#define Kseg 16         // segments per sequence (waves = Bn*Kseg)
#define WPB 4           // waves per block (256-thread blocks)
#define BURN 16         // burn-in steps: direction converges ~0.35^16 ≈ 3e-8

typedef _Float16 h2 __attribute__((ext_vector_type(2)));
typedef _Float16 h8 __attribute__((ext_vector_type(8)));

#if __has_builtin(__builtin_amdgcn_fdot2)
__device__ __forceinline__ float fdot2f(h2 a, h2 b, float c) {
    return __builtin_amdgcn_fdot2(a, b, c, false);
}
#else
__device__ __forceinline__ float fdot2f(h2 a, h2 b, float c) {
    return fmaf((float)a[0], (float)b[0], fmaf((float)a[1], (float)b[1], c));
}
#endif

__device__ __forceinline__ float wave_sum(float v) {
#pragma unroll
    for (int off = 32; off >= 1; off >>= 1) v += __shfl_xor(v, off, 64);
    return v;
}

// One wave = one (batch, segment); WPB waves per block, independent (no barriers).
// Segment s covers steps t in [a_s, a_{s+1}) of the forward recursion
// u_t = E^T diag(exp(emit_{t-1})) u_{t-1}.
// s>0 starts from u=1 and runs BURN warm-up steps (Birkhoff contraction makes
// the direction exact to fp32 by then); contribution log(sum u_end) - S*ln2
// - log(sum u_start) is scale-invariant and telescopes to logZ.
// NOTE: no min-waves clause in launch_bounds — forcing 8 waves/EU capped the
// allocator at 32 VGPRs and spilled E2[32]+pipeline state to scratch
// (R1: WRITE_SIZE 128B -> 114MB, dur 2x). Natural allocation is ~52 VGPRs,
// which already permits 8 waves/SIMD.
__global__ __launch_bounds__(WPB * 64) void crf_seg(
    const float* __restrict__ emit,
    const int*   __restrict__ target,
    const int*   __restrict__ mask,
    const float* __restrict__ trans,
    const float* __restrict__ strans,
    const float* __restrict__ etrans,
    float*       __restrict__ out)
{
    __shared__ __align__(16) _Float16 pbuf[WPB][Nn];

    const int lane = threadIdx.x & 63;
    const int wid  = threadIdx.x >> 6;
    const int gw   = blockIdx.x * WPB + wid;   // global wave id
    const int b    = gw & (Bn - 1);
    const int s    = gw >> 9;                  // 0..Kseg-1

    // E column j (j = lane) as fp16 pairs over i
    h2 E2[32];
#pragma unroll
    for (int m = 0; m < 32; ++m) {
        float x0 = trans[(2 * m) * Nn + lane];
        float x1 = trans[(2 * m + 1) * Nn + lane];
        h2 e; e[0] = (_Float16)__expf(x0); e[1] = (_Float16)__expf(x1);
        E2[m] = e;
    }

    // len = popcount of prefix mask
    const int* mrow = mask + (size_t)b * Tn;
    int lsum = 0;
#pragma unroll
    for (int k = 0; k < Tn / Nn; ++k) lsum += mrow[k * Nn + lane];
#pragma unroll
    for (int off = 32; off >= 1; off >>= 1) lsum += __shfl_xor(lsum, off, 64);
    const int len = lsum;                      // in [512, 1024]

    // segment bounds (identical arithmetic in every wave of this b)
    const int a_s = (s * len) >> 4;            // Kseg = 16
    const int a_e = ((s + 1) * len) >> 4;      // s=15 -> len
    const int tb   = s ? (a_s - BURN) : 1;     // first executed step
    const int tend = a_e - 1;                  // last executed step
    const int rec_t = s ? a_s : -1;            // record point (never hits for s=0)

    const size_t ebase = (size_t)b * Tn * Nn;

    float uu = s ? 1.0f : __expf(strans[lane]);
    int   S  = 0;
    float L0 = 0.0f;

    // w pipeline: wC[q] = exp(emit row tb-1+q); eN = raw rows tb+7..tb+14
    float wC[8], eN[8];
#pragma unroll
    for (int q = 0; q < 8; ++q) wC[q] = emit[ebase + (size_t)(tb - 1 + q) * Nn + lane];
#pragma unroll
    for (int q = 0; q < 8; ++q) eN[q] = emit[ebase + (size_t)(tb + 7 + q) * Nn + lane];
#pragma unroll
    for (int q = 0; q < 8; ++q) wC[q] = __expf(wC[q]);

    _Float16* pb = pbuf[wid];
    auto step = [&](float w) {
        int bits = __builtin_amdgcn_readfirstlane(__float_as_int(uu));
        int mk   = 127 - ((bits >> 23) & 0xff);
        S += mk;
        float p = ldexpf(uu, mk) * w;          // p in (0, ~1300) -> fp16 safe
        pb[lane] = (_Float16)p;

        const h8* pb8 = (const h8*)pb;         // 8 broadcast b128 reads, in-order DS
        float a0 = 0.f, a1 = 0.f, a2 = 0.f, a3 = 0.f;
        float a4 = 0.f, a5 = 0.f, a6 = 0.f, a7 = 0.f;
#pragma unroll
        for (int r = 0; r < 8; r += 2) {
            h8 v0 = pb8[r], v1 = pb8[r + 1];
            a0 = fdot2f(__builtin_shufflevector(v0, v0, 0, 1), E2[4 * r + 0], a0);
            a1 = fdot2f(__builtin_shufflevector(v0, v0, 2, 3), E2[4 * r + 1], a1);
            a2 = fdot2f(__builtin_shufflevector(v0, v0, 4, 5), E2[4 * r + 2], a2);
            a3 = fdot2f(__builtin_shufflevector(v0, v0, 6, 7), E2[4 * r + 3], a3);
            a4 = fdot2f(__builtin_shufflevector(v1, v1, 0, 1), E2[4 * r + 4], a4);
            a5 = fdot2f(__builtin_shufflevector(v1, v1, 2, 3), E2[4 * r + 5], a5);
            a6 = fdot2f(__builtin_shufflevector(v1, v1, 4, 5), E2[4 * r + 6], a6);
            a7 = fdot2f(__builtin_shufflevector(v1, v1, 6, 7), E2[4 * r + 7], a7);
        }
        uu = ((a0 + a1) + (a2 + a3)) + ((a4 + a5) + (a6 + a7));
    };

    int t0 = tb;
    while (t0 + 8 <= tend + 1) {
#pragma unroll
        for (int q = 0; q < 8; ++q) step(wC[q]);
#pragma unroll
        for (int q = 0; q < 8; ++q) wC[q] = __expf(eN[q]);
#pragma unroll
        for (int q = 0; q < 8; ++q) {
            int idx = t0 + 15 + q; if (idx > tend - 1) idx = tend - 1;
            eN[q] = emit[ebase + (size_t)idx * Nn + lane];
        }
        t0 += 8;
        if (t0 == rec_t) {                    // burn-in done: u = c*v_{a_s-1}
            L0 = __logf(wave_sum(uu));
            S = 0;
        }
    }
#pragma unroll
    for (int q = 0; q < 8; ++q)
        if (t0 + q <= tend) step(wC[q]);

    // segment logZ contribution
    float lend;
    if (s == Kseg - 1) {
        float eL = emit[ebase + (size_t)(len - 1) * Nn + lane];
        lend = __logf(wave_sum(uu * __expf(eL + etrans[lane])));
    } else {
        lend = __logf(wave_sum(uu));
    }
    float contrib = lend - (float)S * 0.6931471805599453f - L0;

    // gold-path score for t in [a_s, a_e)  (s=0: [0, a_1))
    const int* trow = target + (size_t)b * Tn;
    const int t_sc = s ? a_s : 0;
    float sc = 0.0f;
#pragma unroll
    for (int k = 0; k < 2; ++k) {             // covers max range 65 (<=128)
        int t = t_sc + k * Nn + lane;
        if (t < a_e) {
            int g = trow[t];
            sc += emit[ebase + (size_t)t * Nn + g];
            if (t > 0) sc += trans[trow[t - 1] * Nn + g];
        }
    }
    sc = wave_sum(sc);

    if (lane == 0) {
        if (s == 0)        sc += strans[trow[0]];
        if (s == Kseg - 1) sc += etrans[trow[len - 1]];
        atomicAdd(out, (contrib - sc) * (1.0f / (float)Bn));
    }
}

extern "C" void kernel_launch(void* const* d_in, const int* in_sizes, int n_in,
                              void* d_out, int out_size, void* d_ws, size_t ws_size,
                              hipStream_t stream) {
    const float* emit   = (const float*)d_in[0];
    const int*   target = (const int*)d_in[1];
    const int*   mask   = (const int*)d_in[2];
    const float* trans  = (const float*)d_in[3];
    const float* strans = (const float*)d_in[4];
    const float* etrans = (const float*)d_in[5];
    float* out = (float*)d_out;

    hipMemsetAsync(out, 0, sizeof(float), stream);
    crf_seg<<<Bn * Kseg / WPB, WPB * 64, 0, stream>>>(emit, target, mask, trans, strans, etrans, out);
}

// Round 6
// 241.646 us; speedup vs baseline: 1.3580x; 1.2045x over previous
//
#include <hip/hip_runtime.h>

#define Bn 512
#define Tn 1024
#define Nn 64
#define BURN 16   // burn-in steps (verified at Kseg=16 in R3: absmax 0.0)

typedef float    f4  __attribute__((ext_vector_type(4)));
typedef __fp16   pk2 __attribute__((ext_vector_type(2)));   // cvt_pkrtz result type
typedef __fp16   pk4 __attribute__((ext_vector_type(4)));
typedef _Float16 h8v __attribute__((ext_vector_type(8)));

__device__ __forceinline__ float wave_sum(float v) {
#pragma unroll
    for (int off = 32; off >= 1; off >>= 1) v += __shfl_xor(v, off, 64);
    return v;
}

// One wave = one batch b; its 16 segments are the 16 columns of a
// 64x64 @ 64x16 MFMA recursion  U' = E^T diag-scaled P,  8 mfma/step.
// Column n covers steps [a_n, a_{n+1}) with BURN warm-up (n>0), exactly the
// R3-verified telescoping scheme, now 16 streams per wave instead of 1.
// LDS is used only for the C-layout -> B-layout shuffle: 4 ds_write_b64 +
// 2 ds_read_b128 per 16 streams (was 9 DS ops per single stream).
__global__ __launch_bounds__(64) void crf_mfma(
    const float* __restrict__ emit,
    const int*   __restrict__ target,
    const int*   __restrict__ mask,
    const float* __restrict__ trans,
    const float* __restrict__ strans,
    const float* __restrict__ etrans,
    float*       __restrict__ out)
{
    __shared__ __align__(16) _Float16 plds[16 * 72];   // col stride 72 halfs = 144B (16B-aligned reads, 2-way banks only)

    const int lane = threadIdx.x;
    const int n = lane & 15;          // stream = MFMA column
    const int g = lane >> 4;          // lane group
    const int b = blockIdx.x;
    const size_t ebase = (size_t)b * Tn * Nn;

    // ---- A fragments: Et[row][k] = exp(trans[k][row]); row = 16r + n, k = 32h + 8g + j
    h8v A[4][2];
#pragma unroll
    for (int r = 0; r < 4; ++r)
#pragma unroll
        for (int h = 0; h < 2; ++h) {
            h8v a;
#pragma unroll
            for (int j = 0; j < 8; ++j)
                a[j] = (_Float16)__expf(trans[(32 * h + 8 * g + j) * Nn + 16 * r + n]);
            A[r][h] = a;
        }

    // ---- len = popcount of prefix mask
    const int* mrow = mask + (size_t)b * Tn;
    int lsum = 0;
#pragma unroll
    for (int k = 0; k < Tn / Nn; ++k) lsum += mrow[k * Nn + lane];
#pragma unroll
    for (int off = 32; off >= 1; off >>= 1) lsum += __shfl_xor(lsum, off, 64);
    const int len = lsum;                       // in [512, 1024]

    // ---- segment bounds for column n
    const int a0    = (n * len) >> 4;
    const int a1    = ((n + 1) * len) >> 4;
    const int start = n ? (a0 - BURN) : 1;      // first executed step t
    const int tendv = a1 - 1;                   // last step t for this column
    const int maxk  = ((len + 15) >> 4) + BURN; // covers all columns' records

    // ---- end weights: only column 15 weights its final colsum by exp(emit[len-1]+etrans)
    float wsel[4][4];
#pragma unroll
    for (int r = 0; r < 4; ++r) {
        f4 ee = *(const f4*)(emit + ebase + (size_t)(len - 1) * Nn + 16 * r + 4 * g);
        f4 et = *(const f4*)(etrans + 16 * r + 4 * g);
#pragma unroll
        for (int c = 0; c < 4; ++c)
            wsel[r][c] = (n == 15) ? __expf(ee[c] + et[c]) : 1.0f;
    }

    // ---- U init (C/D layout: row = 16r + 4g + c, col n). u_{start-1}.
    float U[4][4];
#pragma unroll
    for (int r = 0; r < 4; ++r) {
        f4 st = *(const f4*)(strans + 16 * r + 4 * g);
#pragma unroll
        for (int c = 0; c < 4; ++c)
            U[r][c] = (n == 0) ? __expf(st[c]) : 1.0f;
    }

    int   S = 0;
    float L0 = 0.0f, contrib = 0.0f;

    // ---- W pipeline (1-deep prefetch): step k consumes emit row start+k-1
    f4 rb[4];
    {
        const int tr = start - 1;               // row for k = 0 (>= 0 always)
        const f4* p = (const f4*)(emit + ebase + (size_t)tr * Nn);
#pragma unroll
        for (int r = 0; r < 4; ++r) rb[r] = p[4 * r + g];
    }
    float Wx[4][4];
#pragma unroll
    for (int r = 0; r < 4; ++r)
#pragma unroll
        for (int c = 0; c < 4; ++c) Wx[r][c] = __expf(rb[r][c]);

    const f4 zero4 = {0.f, 0.f, 0.f, 0.f};
    _Float16* myCol = plds + n * 72;

    for (int k = 0; k < maxk; ++k) {
        // issue next step's raw emit rows (chain-independent; hides under body)
        {
            int tr = start + k;                 // row for step k+1
            if (tr > Tn - 1) tr = Tn - 1;       // frozen columns: clamp (unused)
            const f4* p = (const f4*)(emit + ebase + (size_t)tr * Nn);
#pragma unroll
            for (int r = 0; r < 4; ++r) rb[r] = p[4 * r + g];
        }

        // burn-in end (wave-uniform k): U = u_{a0-1}; record L0, reset S (cols n>0)
        if (k == BURN) {
            float cs = 0.f;
#pragma unroll
            for (int r = 0; r < 4; ++r)
#pragma unroll
                for (int c = 0; c < 4; ++c) cs += U[r][c];
            cs += __shfl_xor(cs, 16, 64);
            cs += __shfl_xor(cs, 32, 64);
            float l0v = __logf(cs);
            if (n) { L0 = l0v; S = 0; }
        }

        // per-column rescale (column values within ~e of each other -> fp16 safe)
        float mx = U[0][0];
#pragma unroll
        for (int r = 0; r < 4; ++r)
#pragma unroll
            for (int c = 0; c < 4; ++c) mx = fmaxf(mx, U[r][c]);
        mx = fmaxf(mx, __shfl_xor(mx, 16, 64));
        mx = fmaxf(mx, __shfl_xor(mx, 32, 64));
        const int mk = 127 - ((__float_as_int(mx) >> 23) & 0xff);
        S += mk;

        // P = U * W * 2^mk -> fp16 -> LDS (col-major [col][row], stride 72 halfs)
#pragma unroll
        for (int r = 0; r < 4; ++r) {
            float p0 = U[r][0] * ldexpf(Wx[r][0], mk);
            float p1 = U[r][1] * ldexpf(Wx[r][1], mk);
            float p2 = U[r][2] * ldexpf(Wx[r][2], mk);
            float p3 = U[r][3] * ldexpf(Wx[r][3], mk);
            pk2 lo = __builtin_amdgcn_cvt_pkrtz(p0, p1);
            pk2 hi = __builtin_amdgcn_cvt_pkrtz(p2, p3);
            pk4 v4 = __builtin_shufflevector(lo, hi, 0, 1, 2, 3);
            *(pk4*)&myCol[16 * r + 4 * g] = v4;
        }

        // B fragments: col n, k-rows {8g..8g+7} and {32+8g..32+8g+7}
        h8v B0 = *(const h8v*)&myCol[8 * g];
        h8v B1 = *(const h8v*)&myCol[32 + 8 * g];

        // U' = Et x P  (8 MFMA; columns independent -> frozen-column junk is contained)
#pragma unroll
        for (int r = 0; r < 4; ++r) {
            f4 acc = __builtin_amdgcn_mfma_f32_16x16x32_f16(A[r][0], B0, zero4, 0, 0, 0);
            acc     = __builtin_amdgcn_mfma_f32_16x16x32_f16(A[r][1], B1, acc,   0, 0, 0);
#pragma unroll
            for (int c = 0; c < 4; ++c) U[r][c] = acc[c];
        }

        // segment-end record (fires on ~3 iterations total)
        bool rec = (start + k) == tendv;
        if (__any(rec)) {
            float cs = 0.f;
#pragma unroll
            for (int r = 0; r < 4; ++r)
#pragma unroll
                for (int c = 0; c < 4; ++c) cs = fmaf(U[r][c], wsel[r][c], cs);
            cs += __shfl_xor(cs, 16, 64);
            cs += __shfl_xor(cs, 32, 64);
            float lv = __logf(cs);
            if (rec) contrib = lv - (float)S * 0.6931471805599453f - L0;
        }

        // exp next W (chain-independent)
#pragma unroll
        for (int r = 0; r < 4; ++r)
#pragma unroll
            for (int c = 0; c < 4; ++c) Wx[r][c] = __expf(rb[r][c]);
    }

    // 4 lanes per column hold identical contrib -> /4
    float tot = wave_sum(contrib) * 0.25f;

    // ---- gold-path score over the whole sequence (one wave handles all of b)
    const int* trow = target + (size_t)b * Tn;
    float sc = 0.0f;
#pragma unroll
    for (int k = 0; k < Tn / Nn; ++k) {
        int t = k * Nn + lane;
        if (t < len) {
            int gT = trow[t];
            sc += emit[ebase + (size_t)t * Nn + gT];
            if (t > 0) sc += trans[trow[t - 1] * Nn + gT];
        }
    }
    sc = wave_sum(sc);

    if (lane == 0) {
        sc += strans[trow[0]] + etrans[trow[len - 1]];
        atomicAdd(out, (tot - sc) * (1.0f / (float)Bn));
    }
}

extern "C" void kernel_launch(void* const* d_in, const int* in_sizes, int n_in,
                              void* d_out, int out_size, void* d_ws, size_t ws_size,
                              hipStream_t stream) {
    const float* emit   = (const float*)d_in[0];
    const int*   target = (const int*)d_in[1];
    const int*   mask   = (const int*)d_in[2];
    const float* trans  = (const float*)d_in[3];
    const float* strans = (const float*)d_in[4];
    const float* etrans = (const float*)d_in[5];
    float* out = (float*)d_out;

    (void)hipMemsetAsync(out, 0, sizeof(float), stream);
    crf_mfma<<<Bn, Nn, 0, stream>>>(emit, target, mask, trans, strans, etrans, out);
}

// Round 7
// 223.858 us; speedup vs baseline: 1.4659x; 1.0795x over previous
//
#include <hip/hip_runtime.h>

#define Bn 512
#define Tn 1024
#define Nn 64
#define BURN 16   // burn-in steps (verified: R3 scalar + R6 MFMA, absmax 0.0)

typedef float    f4  __attribute__((ext_vector_type(4)));
typedef __fp16   pk2 __attribute__((ext_vector_type(2)));   // cvt_pkrtz result type
typedef __fp16   pk4 __attribute__((ext_vector_type(4)));
typedef __fp16   pk8 __attribute__((ext_vector_type(8)));
typedef _Float16 h8v __attribute__((ext_vector_type(8)));

__device__ __forceinline__ float wave_sum(float v) {
#pragma unroll
    for (int off = 32; off >= 1; off >>= 1) v += __shfl_xor(v, off, 64);
    return v;
}

// One wave = one batch b; 16 segments = 16 columns of a 64x64 @ 64x16 MFMA
// recursion U' = E^T diag-scaled P (8 mfma/step). R6 structure, two changes:
//   1. NO LDS: B's k-slot map is chosen as k = 32h + 16*(j>>2) + 4g + (j&3),
//      which equals the C/D layout each lane already holds (rows 16r+4g+c of
//      col n). A is loaded with the same k-map, so the contraction is
//      identical (k-map cancels when A and B agree). B = in-register pack.
//   2. Depth-8 register ring for emit rows (unroll-8 keeps indices static):
//      load->use gap = 8 steps (~2000cy) covers HBM latency; ~4x bytes in
//      flight vs R6's 1-deep (R6 measured ~1 TB/s effective = the 90us).
__global__ __launch_bounds__(64) void crf_mfma(
    const float* __restrict__ emit,
    const int*   __restrict__ target,
    const int*   __restrict__ mask,
    const float* __restrict__ trans,
    const float* __restrict__ strans,
    const float* __restrict__ etrans,
    float*       __restrict__ out)
{
    const int lane = threadIdx.x;
    const int n = lane & 15;          // stream = MFMA column (and A row idx)
    const int g = lane >> 4;          // lane group
    const int b = blockIdx.x;
    const size_t ebase = (size_t)b * Tn * Nn;

    // ---- A fragments with k-map k = 32h + 16*(j>>2) + 4g + (j&3)
    // Et[row][k] = exp(trans[k][row]); row = 16r + n
    h8v A[4][2];
#pragma unroll
    for (int r = 0; r < 4; ++r)
#pragma unroll
        for (int h = 0; h < 2; ++h) {
            h8v a;
#pragma unroll
            for (int j = 0; j < 8; ++j) {
                int kk = 32 * h + 16 * (j >> 2) + 4 * g + (j & 3);
                a[j] = (_Float16)__expf(trans[kk * Nn + 16 * r + n]);
            }
            A[r][h] = a;
        }

    // ---- len = popcount of prefix mask
    const int* mrow = mask + (size_t)b * Tn;
    int lsum = 0;
#pragma unroll
    for (int k = 0; k < Tn / Nn; ++k) lsum += mrow[k * Nn + lane];
#pragma unroll
    for (int off = 32; off >= 1; off >>= 1) lsum += __shfl_xor(lsum, off, 64);
    const int len = lsum;                       // in [512, 1024]

    // ---- segment bounds for column n
    const int a0    = (n * len) >> 4;
    const int a1    = ((n + 1) * len) >> 4;
    const int start = n ? (a0 - BURN) : 1;      // first executed step t
    const int tendv = a1 - 1;                   // last step t for this column
    const int maxk  = ((len + 15) >> 4) + BURN; // covers all columns' records

    // ---- end weights: only column 15 weights its final colsum
    float wsel[4][4];
#pragma unroll
    for (int r = 0; r < 4; ++r) {
        f4 ee = *(const f4*)(emit + ebase + (size_t)(len - 1) * Nn + 16 * r + 4 * g);
        f4 et = *(const f4*)(etrans + 16 * r + 4 * g);
#pragma unroll
        for (int c = 0; c < 4; ++c)
            wsel[r][c] = (n == 15) ? __expf(ee[c] + et[c]) : 1.0f;
    }

    // ---- U init (C/D layout: row = 16r + 4g + c, col n). u_{start-1}.
    float U[4][4];
#pragma unroll
    for (int r = 0; r < 4; ++r) {
        f4 st = *(const f4*)(strans + 16 * r + 4 * g);
#pragma unroll
        for (int c = 0; c < 4; ++c)
            U[r][c] = (n == 0) ? __expf(st[c]) : 1.0f;
    }

    int   S = 0;
    float L0 = 0.0f, contrib = 0.0f;

    // ---- depth-8 prefetch ring: rbuf[q] holds raw emit row (start + 8*kb + q - 1)
    f4 rbuf[8][4];
#pragma unroll
    for (int d = 0; d < 8; ++d) {
        int tr = start - 1 + d; if (tr > Tn - 1) tr = Tn - 1;
        const f4* p = (const f4*)(emit + ebase + (size_t)tr * Nn);
#pragma unroll
        for (int r = 0; r < 4; ++r) rbuf[d][r] = p[4 * r + g];
    }

    const f4 zero4 = {0.f, 0.f, 0.f, 0.f};
    const int nkb = (maxk + 7) >> 3;            // extra steps are harmless:
                                                // rescale bounds U, records latch on ==

    for (int kb = 0; kb < nkb; ++kb) {
#pragma unroll
        for (int q = 0; q < 8; ++q) {
            const int k = 8 * kb + q;

            // W for this step (row start+k-1), then refill slot q (row start+k+7)
            float Wx[4][4];
#pragma unroll
            for (int r = 0; r < 4; ++r)
#pragma unroll
                for (int c = 0; c < 4; ++c) Wx[r][c] = __expf(rbuf[q][r][c]);
            {
                int tr = start + k + 7; if (tr > Tn - 1) tr = Tn - 1;
                const f4* p = (const f4*)(emit + ebase + (size_t)tr * Nn);
#pragma unroll
                for (int r = 0; r < 4; ++r) rbuf[q][r] = p[4 * r + g];
            }

            // burn-in end: U = u_{a0-1}; record L0, reset S (cols n>0)
            if (k == BURN) {
                float cs = 0.f;
#pragma unroll
                for (int r = 0; r < 4; ++r)
#pragma unroll
                    for (int c = 0; c < 4; ++c) cs += U[r][c];
                cs += __shfl_xor(cs, 16, 64);
                cs += __shfl_xor(cs, 32, 64);
                float l0v = __logf(cs);
                if (n) { L0 = l0v; S = 0; }
            }

            // per-column rescale: mx = col max -> mx*2^mk in [1,2)
            float m0 = fmaxf(fmaxf(U[0][0], U[0][1]), fmaxf(U[0][2], U[0][3]));
            float m1 = fmaxf(fmaxf(U[1][0], U[1][1]), fmaxf(U[1][2], U[1][3]));
            float m2 = fmaxf(fmaxf(U[2][0], U[2][1]), fmaxf(U[2][2], U[2][3]));
            float m3 = fmaxf(fmaxf(U[3][0], U[3][1]), fmaxf(U[3][2], U[3][3]));
            float mx = fmaxf(fmaxf(m0, m1), fmaxf(m2, m3));
            mx = fmaxf(mx, __shfl_xor(mx, 16, 64));
            mx = fmaxf(mx, __shfl_xor(mx, 32, 64));
            const int mk = 127 - ((__float_as_int(mx) >> 23) & 0xff);
            S += mk;
            const float sc2 = __int_as_float((127 + mk) << 23);   // 2^mk, mk in (-30, 1]

            // p = U * 2^mk * W -> fp16, packed in-register as B (k-map above)
            float P_[4][4];
#pragma unroll
            for (int r = 0; r < 4; ++r)
#pragma unroll
                for (int c = 0; c < 4; ++c) P_[r][c] = U[r][c] * sc2 * Wx[r][c];

            pk2 c00 = __builtin_amdgcn_cvt_pkrtz(P_[0][0], P_[0][1]);
            pk2 c01 = __builtin_amdgcn_cvt_pkrtz(P_[0][2], P_[0][3]);
            pk2 c10 = __builtin_amdgcn_cvt_pkrtz(P_[1][0], P_[1][1]);
            pk2 c11 = __builtin_amdgcn_cvt_pkrtz(P_[1][2], P_[1][3]);
            pk2 c20 = __builtin_amdgcn_cvt_pkrtz(P_[2][0], P_[2][1]);
            pk2 c21 = __builtin_amdgcn_cvt_pkrtz(P_[2][2], P_[2][3]);
            pk2 c30 = __builtin_amdgcn_cvt_pkrtz(P_[3][0], P_[3][1]);
            pk2 c31 = __builtin_amdgcn_cvt_pkrtz(P_[3][2], P_[3][3]);
            pk4 b0lo = __builtin_shufflevector(c00, c01, 0, 1, 2, 3);
            pk4 b0hi = __builtin_shufflevector(c10, c11, 0, 1, 2, 3);
            pk4 b1lo = __builtin_shufflevector(c20, c21, 0, 1, 2, 3);
            pk4 b1hi = __builtin_shufflevector(c30, c31, 0, 1, 2, 3);
            pk8 b0p = __builtin_shufflevector(b0lo, b0hi, 0, 1, 2, 3, 4, 5, 6, 7);
            pk8 b1p = __builtin_shufflevector(b1lo, b1hi, 0, 1, 2, 3, 4, 5, 6, 7);
            h8v B0 = __builtin_bit_cast(h8v, b0p);
            h8v B1 = __builtin_bit_cast(h8v, b1p);

            // U' = Et x P  (8 MFMA, no LDS anywhere)
#pragma unroll
            for (int r = 0; r < 4; ++r) {
                f4 acc = __builtin_amdgcn_mfma_f32_16x16x32_f16(A[r][0], B0, zero4, 0, 0, 0);
                acc     = __builtin_amdgcn_mfma_f32_16x16x32_f16(A[r][1], B1, acc,   0, 0, 0);
#pragma unroll
                for (int c = 0; c < 4; ++c) U[r][c] = acc[c];
            }

            // segment-end record (fires on ~2-3 iterations total)
            bool rec = (start + k) == tendv;
            if (__any(rec)) {
                float cs = 0.f;
#pragma unroll
                for (int r = 0; r < 4; ++r)
#pragma unroll
                    for (int c = 0; c < 4; ++c) cs = fmaf(U[r][c], wsel[r][c], cs);
                cs += __shfl_xor(cs, 16, 64);
                cs += __shfl_xor(cs, 32, 64);
                float lv = __logf(cs);
                if (rec) contrib = lv - (float)S * 0.6931471805599453f - L0;
            }
        }
    }

    // 4 lanes per column hold identical contrib -> /4
    float tot = wave_sum(contrib) * 0.25f;

    // ---- gold-path score over the whole sequence (one wave handles all of b)
    const int* trow = target + (size_t)b * Tn;
    float sc = 0.0f;
#pragma unroll
    for (int k = 0; k < Tn / Nn; ++k) {
        int t = k * Nn + lane;
        if (t < len) {
            int gT = trow[t];
            sc += emit[ebase + (size_t)t * Nn + gT];
            if (t > 0) sc += trans[trow[t - 1] * Nn + gT];
        }
    }
    sc = wave_sum(sc);

    if (lane == 0) {
        sc += strans[trow[0]] + etrans[trow[len - 1]];
        atomicAdd(out, (tot - sc) * (1.0f / (float)Bn));
    }
}

extern "C" void kernel_launch(void* const* d_in, const int* in_sizes, int n_in,
                              void* d_out, int out_size, void* d_ws, size_t ws_size,
                              hipStream_t stream) {
    const float* emit   = (const float*)d_in[0];
    const int*   target = (const int*)d_in[1];
    const int*   mask   = (const int*)d_in[2];
    const float* trans  = (const float*)d_in[3];
    const float* strans = (const float*)d_in[4];
    const float* etrans = (const float*)d_in[5];
    float* out = (float*)d_out;

    (void)hipMemsetAsync(out, 0, sizeof(float), stream);
    crf_mfma<<<Bn, Nn, 0, stream>>>(emit, target, mask, trans, strans, etrans, out);
}